// Round 11
// baseline (443.369 us; speedup 1.0000x reference)
//
#include <hip/hip_runtime.h>
#include <math.h>

#define CDIM 32
#define HWDIM 2304            // 48*48
#define BDIM 16
#define PPW 8                 // pixels per wave (8 lanes per pixel)
#define NTHREADS 256          // 4 waves => 32 pixels per batch
#define PPB 32
#define BATCH 2               // pixel batches per block (fetch amortization)
#define ZOFF (BDIM * CDIM * HWDIM)   // z elements, then 16 logdet floats

// R10 lesson: duration tracks (#waves x unrolled-body-bytes) across R3/R5/
// R7/R10 regardless of instruction mix -> instruction-FETCH bound (~30KB
// straight-line solver streamed through a ~32KB shared I$ by every wave).
// R11: same proven structure (R3 staging + R3 right-looking algebra + R7
// DPP bcast8, 8 lanes/pixel, (256,2)), but each block solves TWO 32-pixel
// batches in a '#pragma unroll 1' loop: grid 1152->576, wave count halves,
// fetch traffic halves; issue/regs/LDS unchanged. Right-looking also drops
// the per-link cndmask left-looking needed (~20% smaller body).
__device__ __forceinline__ void gload_lds16(const float* g, float* l) {
    __builtin_amdgcn_global_load_lds(
        (const __attribute__((address_space(1))) float*)g,
        (__attribute__((address_space(3))) float*)l, 16, 0, 0);
}

// Broadcast lane (group_base + k7) to all 8 lanes of each aligned 8-lane
// group (R7-proven DPP pair; k7 compile-time, call sites fully unrolled).
// Step1 quad_perm([s,s,s,s]), s=k7&3. Step2: k7<4: row_shr:4 mask 0xA
// (odd quads <- even); k7>=4: row_shl:4 mask 0x5 (even <- odd).
__device__ __forceinline__ float bcast8(float x, int k7) {
    int v = __float_as_int(x), b;
    switch (k7) {
    case 0: b = __builtin_amdgcn_update_dpp(v, v, 0x00, 0xF, 0xF, false);
            b = __builtin_amdgcn_update_dpp(b, b, 0x114, 0xF, 0xA, false); break;
    case 1: b = __builtin_amdgcn_update_dpp(v, v, 0x55, 0xF, 0xF, false);
            b = __builtin_amdgcn_update_dpp(b, b, 0x114, 0xF, 0xA, false); break;
    case 2: b = __builtin_amdgcn_update_dpp(v, v, 0xAA, 0xF, 0xF, false);
            b = __builtin_amdgcn_update_dpp(b, b, 0x114, 0xF, 0xA, false); break;
    case 3: b = __builtin_amdgcn_update_dpp(v, v, 0xFF, 0xF, 0xF, false);
            b = __builtin_amdgcn_update_dpp(b, b, 0x114, 0xF, 0xA, false); break;
    case 4: b = __builtin_amdgcn_update_dpp(v, v, 0x00, 0xF, 0xF, false);
            b = __builtin_amdgcn_update_dpp(b, b, 0x104, 0xF, 0x5, false); break;
    case 5: b = __builtin_amdgcn_update_dpp(v, v, 0x55, 0xF, 0xF, false);
            b = __builtin_amdgcn_update_dpp(b, b, 0x104, 0xF, 0x5, false); break;
    case 6: b = __builtin_amdgcn_update_dpp(v, v, 0xAA, 0xF, 0xF, false);
            b = __builtin_amdgcn_update_dpp(b, b, 0x104, 0xF, 0x5, false); break;
    default: b = __builtin_amdgcn_update_dpp(v, v, 0xFF, 0xF, 0xF, false);
            b = __builtin_amdgcn_update_dpp(b, b, 0x104, 0xF, 0x5, false); break;
    }
    return __int_as_float(b);
}

__global__ __launch_bounds__(NTHREADS, 2)
void solve_kernel(const float* __restrict__ input,
                  const float* __restrict__ weight,
                  const float* __restrict__ logdet,
                  float* __restrict__ out) {
    const int t    = threadIdx.x;
    const int lane = t & 63;
    const int wv   = t >> 6;           // wave 0..3
    const int h    = lane & 7;         // row class: owns rows i = 8r + h
    const int p    = lane >> 3;        // pixel-in-wave 0..7

    const int blk  = blockIdx.x;
    const int BPI  = HWDIM / (PPB * BATCH);     // 36 blocks per batch image
    const int b    = blk / BPI;
    const int pbB  = (blk % BPI) * (PPB * BATCH);  // block pixel base (64-wide)
    const int pixl = wv * PPW + p;              // pixel-in-batch 0..31

    __shared__ float lds[2][256 * CDIM];        // 2 x 32KB chunk ring

    const int sg = lane >> 3;
    const int sp = lane & 7;
    const int ps = pixl >> 2, pc = pixl & 3;

    // fetch-amortization loop: body executes twice from I$, halving the
    // per-block instruction-stream traffic per pixel. MUST NOT unroll.
    #pragma unroll 1
    for (int bt = 0; bt < BATCH; ++bt) {
        const int pbt  = pbB + bt * PPB;        // this batch's pixel base
        const int pix  = pbt + pixl;
        const int pix0 = pbt + wv * PPW;        // wave pixel base (logdet)

        // ---- x: scalar loads, issued first (oldest in vmcnt order) ----
        const float* xp = input + (size_t)b * CDIM * HWDIM
                                + (size_t)h * HWDIM + pix;
        float y[4];
        #pragma unroll
        for (int r = 0; r < 4; ++r) y[r] = xp[(size_t)(r * 8) * HWDIM];
        asm volatile("" ::: "memory");

        // ---- DMA staging (R3-verbatim): chunk r = rc-rows [256r,256r+256) --
        // rcl = wv*64 + q*8 + sg; LDS dest linear (word rcl*32 + sp*4);
        // global source slot pre-swizzled by g = rcl>>5 (wave-uniform per q
        // -> full 128B lines). Read: A[r][j] at word (h*32+j)*32+((ps^h)<<2)+pc.
        const float* wbase = weight + (size_t)b * (CDIM * CDIM) * HWDIM + pbt;
        const float* srcA = wbase + (size_t)(wv * 64 + sg) * HWDIM
                                  + ((sp ^ (2 * wv)) << 2);
        const float* srcB = wbase + (size_t)(wv * 64 + sg) * HWDIM
                                  + ((sp ^ (2 * wv + 1)) << 2);

        auto stage = [&](int r, int buf) {
            float* lbase = &lds[buf][(wv * 64) * CDIM];
            #pragma unroll
            for (int q = 0; q < 8; ++q) {
                const float* s = (q < 4 ? srcA : srcB)
                               + (size_t)(r * 256 + q * 8) * HWDIM;
                gload_lds16(s, lbase + q * 8 * CDIM);
            }
        };

        stage(0, 0);
        asm volatile("" ::: "memory");
        stage(1, 1);

        float A[4][CDIM];
        #pragma unroll
        for (int r = 0; r < 4; ++r) {
            if (r < 3) asm volatile("s_waitcnt vmcnt(8)" ::: "memory");
            else       asm volatile("s_waitcnt vmcnt(0)" ::: "memory");
            __builtin_amdgcn_s_barrier();
            asm volatile("" ::: "memory");
            #pragma unroll
            for (int j = 0; j < CDIM; ++j)
                A[r][j] = lds[r & 1][(h * CDIM + j) * CDIM
                                     + ((ps ^ h) << 2) + pc];
            if (r < 2) {
                asm volatile("s_waitcnt lgkmcnt(0)" ::: "memory");
                __builtin_amdgcn_s_barrier();
                asm volatile("" ::: "memory");
                stage(r + 2, r & 1);
            }
        }

        // ---- right-looking LU, no pivoting (R3-verbatim algebra; owner row
        // scaled to unit diagonal via m_owner = 1-r) ----
        float lacc = 0.0f;
        #pragma unroll
        for (int k = 0; k < CDIM; ++k) {
            const int tr = k >> 3, k7 = k & 7;
            float bp = bcast8(A[tr][k], k7);
            float r  = __builtin_amdgcn_rcpf(bp);
            lacc += __log2f(fabsf(bp));

            float m[4];
            m[tr] = (h > k7) ? A[tr][k] * r : ((h == k7) ? (1.0f - r) : 0.0f);
            #pragma unroll
            for (int q = tr + 1; q < 4; ++q) m[q] = A[q][k] * r;

            #pragma unroll
            for (int j = k + 1; j < CDIM; ++j) {
                float bv = bcast8(A[tr][j], k7);
                #pragma unroll
                for (int q = tr; q < 4; ++q)
                    A[q][j] = fmaf(-m[q], bv, A[q][j]);
            }
            float bq = bcast8(y[tr], k7);
            #pragma unroll
            for (int q = tr; q < 4; ++q) y[q] = fmaf(-m[q], bq, y[q]);
        }

        // ---- back-substitution (unit-diagonal U after owner scaling) ----
        #pragma unroll
        for (int k = CDIM - 1; k >= 1; --k) {
            const int tr = k >> 3, k7 = k & 7;
            float bz = bcast8(y[tr], k7);
            float cm = (h < k7) ? A[tr][k] : 0.0f;
            y[tr] = fmaf(-cm, bz, y[tr]);
            #pragma unroll
            for (int q = 0; q < tr; ++q)
                y[q] = fmaf(-A[q][k], bz, y[q]);
        }
        // y[r] = z[8r + h]

        // ---- store z (dense 32B-segment pattern) ----
        float* zp = out + (size_t)b * CDIM * HWDIM + (size_t)h * HWDIM + pix;
        #pragma unroll
        for (int r = 0; r < 4; ++r) zp[(size_t)(r * 8) * HWDIM] = y[r];

        // ---- logdet: lacc identical across a pixel's 8 lanes; 3 xor-
        // shuffles sum the wave's 8 pixel-groups; one atomic per wave. ----
        float v2 = lacc;
        v2 += __shfl_xor(v2, 8);
        v2 += __shfl_xor(v2, 16);
        v2 += __shfl_xor(v2, 32);
        if (lane == 0) {
            float add = -v2 * 0.69314718055994531f;  // ln2 * sum(log2|piv|)
            if (pix0 == 0) add += logdet[b];         // once per b (bt=0,blk%36=0,wv=0)
            atomicAdd(&out[ZOFF + b], add);
        }

        // all waves done with this batch's LDS before next batch re-stages
        __builtin_amdgcn_s_barrier();
        asm volatile("" ::: "memory");
    }
}

extern "C" void kernel_launch(void* const* d_in, const int* in_sizes, int n_in,
                              void* d_out, int out_size, void* d_ws, size_t ws_size,
                              hipStream_t stream) {
    const float* input  = (const float*)d_in[0];
    const float* weight = (const float*)d_in[1];
    const float* logdet = (const float*)d_in[2];
    float* out = (float*)d_out;

    solve_kernel<<<BDIM * (HWDIM / (PPB * BATCH)), NTHREADS, 0, stream>>>(
        input, weight, logdet, out);
}